// Round 6
// baseline (2762.820 us; speedup 1.0000x reference)
//
#include <hip/hip_runtime.h>

// Fused ST-attention block for MI355X (gfx950).
// Round 4 (resubmit x2): LDS diet (149KB -> 71.8KB) for 2 blocks/CU.
// Activations bf16-hi; weights hi/lo (2 MFMA per tile). Attention fp32 regs.

#define N_ 64
#define C_ 256
#define T_ 120
#define V_ 25
#define H_ 8
#define HD_ 32
#define K_ 5
#define TV_ 3000
#define CTV_ 768000

typedef unsigned short u16;
typedef __bf16 bf16x8 __attribute__((ext_vector_type(8)));
typedef float f32x4 __attribute__((ext_vector_type(4)));
typedef u16 u16x4 __attribute__((ext_vector_type(4)));

#define MFMA(a, b, c) __builtin_amdgcn_mfma_f32_16x16x32_bf16(a, b, c, 0, 0, 0)

__device__ __forceinline__ u16 bhi(float f) {
    union { float f; unsigned u; } c; c.f = f; return (u16)(c.u >> 16);
}
__device__ __forceinline__ float bhif(float f) {
    union { float f; unsigned u; } c; c.f = f; c.u &= 0xFFFF0000u; return c.f;
}
__device__ __forceinline__ float b2f(u16 u) {
    union { unsigned u; float f; } c; c.u = ((unsigned)u) << 16; return c.f;
}

// ---- LDS layout: one u16 array, offsets in u16 units ----
// R0 [0:13264)      : xT f32 [25][264] -> { q u16 [256][28] | Z2 f32 @7168 | QR f32 @11264 } -> o u16 [25][264]
// R1 [13264:19864)  : xn u16 [25][264] -> AT u16 [200][28]
// R2 [19864:27032)  : zT u16 [16][264] -> e/k u16 [256][28]
// R3 [27032:34232)  : PS/PSS f32 [512] -> v u16 [8][25][36]
// small [34232:...) : JL, INV, W1, MU, RS, BIAS (f32), HOPS (int)
#define U_XT 0
#define U_Q 0
#define U_O 0
#define U_Z2 7168
#define U_QR 11264
#define U_XN 13264
#define U_AT 13264
#define U_ZT 19864
#define U_K 19864
#define U_PS 27032
#define U_V 27032
#define U_JL 34232
#define U_INV 34482
#define U_W1 34492
#define U_MU 35004
#define U_RS 35054
#define U_BIAS 35104
#define U_HOPS 35504
#define SMEM_U 36768        // 73,536 bytes -> 2 blocks/CU

// ---- ws layout (u16 units): MFMA-swizzled weight fragments (hi[8]|lo[8] per frag) ----
// frag(mt,kt,lane): elem j -> W[16*mt+(lane&15)][32*kt+8*(lane>>4)+j]
#define WS_Q 0              // 48 mt * 8 kt * 64 * 16 = 393216
#define WS_PE 393216        // 16 mt -> 131072
#define WS_PJ 524288        // 16 mt -> 131072

__global__ __launch_bounds__(256) void wprep(
    const float* __restrict__ qw, const float* __restrict__ kvw,
    const float* __restrict__ pew, const float* __restrict__ pjw,
    u16* __restrict__ ws)
{
    int fid = blockIdx.x * 256 + threadIdx.x;   // 0..40959
    int seg, f;
    if (fid < 24576)      { seg = 0; f = fid; }
    else if (fid < 32768) { seg = 1; f = fid - 24576; }
    else                  { seg = 2; f = fid - 32768; }
    int mt = f >> 9, rem = f & 511, kt = rem >> 6, l = rem & 63;
    int row = mt * 16 + (l & 15);
    int k0 = kt * 32 + (l >> 4) * 8;
    const float* sp;
    u16* dp;
    if (seg == 0) {
        sp = (row < 256) ? (qw + row * 256 + k0) : (kvw + (row - 256) * 256 + k0);
        dp = ws + WS_Q + f * 16;
    } else if (seg == 1) {
        sp = pew + row * 256 + k0;
        dp = ws + WS_PE + f * 16;
    } else {
        sp = pjw + row * 256 + k0;
        dp = ws + WS_PJ + f * 16;
    }
    float4 a = *(const float4*)sp;
    float4 b = *(const float4*)(sp + 4);
    float w8[8] = {a.x, a.y, a.z, a.w, b.x, b.y, b.z, b.w};
    #pragma unroll
    for (int j = 0; j < 8; ++j) {
        float w = w8[j];
        dp[j] = bhi(w);
        dp[8 + j] = bhi(w - bhif(w));
    }
}

__global__ __launch_bounds__(512, 4) void fused_sttr(
    const float* __restrict__ x, const float* __restrict__ jl,
    const int* __restrict__ hops, const float* __restrict__ n1w,
    const float* __restrict__ n1b, const float* __restrict__ rpe,
    const float* __restrict__ pjb, const float* __restrict__ w1,
    const float* __restrict__ outer, const float* __restrict__ alpha,
    const u16* __restrict__ ws, float* __restrict__ out)
{
    __shared__ u16 smu[SMEM_U];
    float* xTf   = (float*)smu;
    float* Z2f   = (float*)(smu + U_Z2);
    float* QRf   = (float*)(smu + U_QR);
    float* PSf   = (float*)(smu + U_PS);
    float* JLf   = (float*)(smu + U_JL);
    float* INVf  = (float*)(smu + U_INV);
    float* W1f   = (float*)(smu + U_W1);
    float* MUf   = (float*)(smu + U_MU);
    float* RSf   = (float*)(smu + U_RS);
    float* BIASf = (float*)(smu + U_BIAS);
    int* hopsS   = (int*)(smu + U_HOPS);

    const int tid = threadIdx.x;
    const int bid = blockIdx.x;
    const int n = bid / T_;
    const int t = bid - n * T_;
    const int xbase = n * CTV_ + t * V_;
    const u16* wsq  = ws + WS_Q;
    const u16* wspe = ws + WS_PE;
    const u16* wspj = ws + WS_PJ;
    const int wv = tid >> 6, ln = tid & 63;
    const int col = ln & 15, kg = ln >> 4;

    // ---- P0: stage tables + x slice (transposed, f32) ----
    for (int i = tid; i < V_ * K_; i += 512) JLf[i] = jl[i];
    for (int i = tid; i < V_ * V_; i += 512) hopsS[i] = hops[i];
    for (int i = tid; i < H_ * HD_; i += 512) W1f[i] = w1[i];
    for (int i = tid; i < C_ * V_; i += 512) {
        int c = i / V_, v = i - c * V_;
        xTf[v * 264 + c] = x[xbase + c * TV_ + v];
    }
    __syncthreads();

    // ---- P1: jl column inv-sums | LN partial sums (PS/PSS in R3) ----
    if (tid < K_) {
        float s = 0.f;
        for (int v = 0; v < V_; ++v) s += JLf[v * K_ + tid];
        INVf[tid] = 1.0f / s;
    } else if (tid >= 256 && tid < 456) {
        int i = tid - 256;
        int v = i % 25, p = i / 25;
        const float* row = &xTf[v * 264 + p * 32];
        float s = 0.f, ss = 0.f;
        #pragma unroll
        for (int j = 0; j < 32; ++j) { float xx = row[j]; s += xx; ss += xx * xx; }
        PSf[p * 32 + v] = s;
        PSf[256 + p * 32 + v] = ss;
    }
    __syncthreads();

    // ---- P2: zT (bf16, direct) | mu/rstd ----
    if (tid < C_) {
        float a0 = 0, a1 = 0, a2 = 0, a3 = 0, a4 = 0;
        #pragma unroll
        for (int v = 0; v < V_; ++v) {
            float xv = xTf[v * 264 + tid];
            const float* j5 = &JLf[v * K_];
            a0 += xv * j5[0]; a1 += xv * j5[1]; a2 += xv * j5[2];
            a3 += xv * j5[3]; a4 += xv * j5[4];
        }
        smu[U_ZT + 0 * 264 + tid] = bhi(a0 * INVf[0]);
        smu[U_ZT + 1 * 264 + tid] = bhi(a1 * INVf[1]);
        smu[U_ZT + 2 * 264 + tid] = bhi(a2 * INVf[2]);
        smu[U_ZT + 3 * 264 + tid] = bhi(a3 * INVf[3]);
        smu[U_ZT + 4 * 264 + tid] = bhi(a4 * INVf[4]);
    } else if (tid < C_ + V_) {
        int v = tid - C_;
        float s = 0.f, ss = 0.f;
        #pragma unroll
        for (int p = 0; p < 8; ++p) { s += PSf[p * 32 + v]; ss += PSf[256 + p * 32 + v]; }
        float mu = s * (1.0f / 256.0f);
        float var = ss * (1.0f / 256.0f) - mu * mu;
        MUf[v] = mu;
        RSf[v] = rsqrtf(var + 1e-5f);
    }
    __syncthreads();

    // ---- P3: xn = LN(x) -> bf16 into R1 (512 thr: c x v-half) ----
    {
        int c = tid & 255, half = tid >> 8;
        int v0 = half ? 12 : 0, v1 = half ? 25 : 12;
        float w = n1w[c], b = n1b[c];
        for (int v = v0; v < v1; ++v) {
            float xv = xTf[v * 264 + c];
            smu[U_XN + v * 264 + c] = bhi((xv - MUf[v]) * RSf[v] * w + b);
        }
    }
    __syncthreads();

    // ---- P4: pe MFMA: z2 = pew @ z ----
    {
        f32x4 zacc[2];
        #pragma unroll
        for (int i = 0; i < 2; ++i)
            #pragma unroll
            for (int r = 0; r < 4; ++r) zacc[i][r] = 0.f;
        for (int kt = 0; kt < 8; ++kt) {
            int bo = kt * 32 + kg * 8;
            bf16x8 zb = *reinterpret_cast<const bf16x8*>(&smu[U_ZT + col * 264 + bo]);
            #pragma unroll
            for (int i = 0; i < 2; ++i) {
                const u16* ap = wspe + (((wv * 2 + i) * 8 + kt) * 64 + ln) * 16;
                bf16x8 ah = *reinterpret_cast<const bf16x8*>(ap);
                bf16x8 al = *reinterpret_cast<const bf16x8*>(ap + 8);
                zacc[i] = MFMA(ah, zb, zacc[i]);
                zacc[i] = MFMA(al, zb, zacc[i]);
            }
        }
        if (col < K_) {
            #pragma unroll
            for (int i = 0; i < 2; ++i)
                #pragma unroll
                for (int r = 0; r < 4; ++r)
                    Z2f[((wv * 2 + i) * 16 + kg * 4 + r) * 8 + col] = zacc[i][r];
        }
    }
    __syncthreads();

    // ---- P4b: e = z2 @ jl^T -> bf16 into K buffer (512 thr: c x v-half) ----
    {
        int c = tid & 255, half = tid >> 8;
        int v0 = half ? 12 : 0, v1 = half ? 25 : 12;
        float z0 = Z2f[c * 8 + 0], z1 = Z2f[c * 8 + 1], z2 = Z2f[c * 8 + 2];
        float z3 = Z2f[c * 8 + 3], z4 = Z2f[c * 8 + 4];
        for (int v = v0; v < v1; ++v) {
            const float* j5 = &JLf[v * K_];
            float e = z0 * j5[0] + z1 * j5[1] + z2 * j5[2] + z3 * j5[3] + z4 * j5[4];
            smu[U_K + c * 28 + v] = bhi(e);
        }
    }
    __syncthreads();

    // ---- P5: qkv MFMA (A=ws_q hi/lo, B=xn hi) ----
    {
        f32x4 acc[6][2];
        #pragma unroll
        for (int i = 0; i < 6; ++i)
            #pragma unroll
            for (int nt = 0; nt < 2; ++nt)
                #pragma unroll
                for (int r = 0; r < 4; ++r) acc[i][nt][r] = 0.f;
        for (int kt = 0; kt < 8; ++kt) {
            int bo = kt * 32 + kg * 8;
            bf16x8 b0 = *reinterpret_cast<const bf16x8*>(&smu[U_XN + col * 264 + bo]);
            bf16x8 b1 = *reinterpret_cast<const bf16x8*>(&smu[U_XN + (col + 16) * 264 + bo]);
            #pragma unroll
            for (int i = 0; i < 6; ++i) {
                const u16* ap = wsq + (((wv * 6 + i) * 8 + kt) * 64 + ln) * 16;
                bf16x8 ah = *reinterpret_cast<const bf16x8*>(ap);
                bf16x8 al = *reinterpret_cast<const bf16x8*>(ap + 8);
                acc[i][0] = MFMA(ah, b0, acc[i][0]);
                acc[i][0] = MFMA(al, b0, acc[i][0]);
                acc[i][1] = MFMA(ah, b1, acc[i][1]);
                acc[i][1] = MFMA(al, b1, acc[i][1]);
            }
        }
        // bias[h][m] = w1 . e  (K buffer still holds pure e)
        if (tid < H_ * V_) {
            int h = tid / V_, m = tid - h * V_;
            float s = 0.f;
            #pragma unroll
            for (int c = 0; c < HD_; ++c)
                s += W1f[h * HD_ + c] * b2f(smu[U_K + (h * HD_ + c) * 28 + m]);
            BIASf[tid] = s;
        }
        __syncthreads();
        // writeback q / k+=e / v  (all bf16)
        #pragma unroll
        for (int i = 0; i < 6; ++i) {
            #pragma unroll
            for (int nt = 0; nt < 2; ++nt) {
                int v = nt * 16 + col;
                if (v < V_) {
                    #pragma unroll
                    for (int r = 0; r < 4; ++r) {
                        int row = (wv * 6 + i) * 16 + kg * 4 + r;
                        float val = acc[i][nt][r];
                        if (row < 256) {
                            smu[U_Q + row * 28 + v] = bhi(val);
                        } else if (row < 512) {
                            int a = U_K + (row - 256) * 28 + v;
                            smu[a] = bhi(b2f(smu[a]) + val);
                        } else {
                            int d = row - 512;
                            smu[U_V + ((d >> 5) * V_ + v) * 36 + (d & 31)] = bhi(val);
                        }
                    }
                }
            }
        }
    }
    __syncthreads();

    // ---- P6: qr[h][n][hop] = q . rpe ----
    for (int i = tid; i < H_ * V_ * K_; i += 512) {
        int h = i / (V_ * K_);
        int rem = i - h * (V_ * K_);
        int nq = rem / K_, hop = rem - nq * K_;
        const float* rp = rpe + hop * 256 + h * HD_;
        float s = 0.f;
        #pragma unroll
        for (int c = 0; c < HD_; ++c)
            s += b2f(smu[U_Q + (h * HD_ + c) * 28 + nq]) * rp[c];
        QRf[(h * V_ + nq) * K_ + hop] = s;
    }
    __syncthreads();

    // ---- P7: attn scores (fp32 regs), 4x4 tiles, write AT bf16 ----
    if (tid < 392) {
        int h = tid / 49;
        int r = tid - h * 49;
        int qg = r / 7, mg = r - qg * 7;
        int q0 = qg * 4, m0 = mg * 4;
        float acc[4][4];
        #pragma unroll
        for (int i = 0; i < 4; ++i)
            #pragma unroll
            for (int j = 0; j < 4; ++j) acc[i][j] = 0.f;
        for (int c = 0; c < HD_; ++c) {
            u16x4 q4 = *(const u16x4*)&smu[U_Q + (h * HD_ + c) * 28 + q0];
            u16x4 k4 = *(const u16x4*)&smu[U_K + (h * HD_ + c) * 28 + m0];
            float qa[4] = {b2f(q4[0]), b2f(q4[1]), b2f(q4[2]), b2f(q4[3])};
            float ka[4] = {b2f(k4[0]), b2f(k4[1]), b2f(k4[2]), b2f(k4[3])};
            #pragma unroll
            for (int i = 0; i < 4; ++i)
                #pragma unroll
                for (int j = 0; j < 4; ++j) acc[i][j] += qa[i] * ka[j];
        }
        #pragma unroll
        for (int i = 0; i < 4; ++i) {
            int nq = q0 + i;
            if (nq < V_) {
                #pragma unroll
                for (int j = 0; j < 4; ++j) {
                    int m = m0 + j;
                    if (m < V_) {
                        int hop = hopsS[nq * V_ + m];
                        float val = acc[i][j] + QRf[(h * V_ + nq) * K_ + hop]
                                  + BIASf[h * V_ + m];
                        smu[U_AT + (h * V_ + nq) * 28 + m] = bhi(val);
                    }
                }
            }
        }
    }
    __syncthreads();

    // ---- P8: softmax (fp32 regs) + mix = alpha*p + outer -> bf16 ----
    if (tid < H_ * V_) {
        int h = tid / V_, nq = tid - h * V_;
        u16* row = &smu[U_AT + (h * V_ + nq) * 28];
        const float sc = 0.17677669529663688f;
        float ev[25];
        float mx = -1e30f;
        #pragma unroll
        for (int j = 0; j < V_; ++j) { ev[j] = b2f(row[j]) * sc; mx = fmaxf(mx, ev[j]); }
        float s = 0.f;
        #pragma unroll
        for (int j = 0; j < V_; ++j) { ev[j] = __expf(ev[j] - mx); s += ev[j]; }
        float inv = alpha[0] / s;
        const float* ob = outer + (h * V_ + nq) * V_;
        #pragma unroll
        for (int j = 0; j < V_; ++j) row[j] = bhi(ev[j] * inv + ob[j]);
    }
    __syncthreads();

    // ---- P9: o = mix @ v -> bf16 into R0 (320 thr) ----
    if (tid < 320) {
        int h = tid / 40, r = tid % 40, ng = r >> 3, cg = r & 7;
        int n0 = ng * 5, c0 = cg * 4;
        float acc[5][4];
        #pragma unroll
        for (int i = 0; i < 5; ++i)
            #pragma unroll
            for (int j = 0; j < 4; ++j) acc[i][j] = 0.f;
        for (int m = 0; m < V_; ++m) {
            u16x4 v4 = *(const u16x4*)&smu[U_V + (h * V_ + m) * 36 + c0];
            float va[4] = {b2f(v4[0]), b2f(v4[1]), b2f(v4[2]), b2f(v4[3])};
            #pragma unroll
            for (int i = 0; i < 5; ++i) {
                float mixv = b2f(smu[U_AT + (h * V_ + n0 + i) * 28 + m]);
                acc[i][0] += mixv * va[0]; acc[i][1] += mixv * va[1];
                acc[i][2] += mixv * va[2]; acc[i][3] += mixv * va[3];
            }
        }
        int cb = h * HD_ + c0;
        #pragma unroll
        for (int i = 0; i < 5; ++i) {
            u16x4 w4;
            #pragma unroll
            for (int j = 0; j < 4; ++j) w4[j] = bhi(acc[i][j]);
            *(u16x4*)&smu[U_O + (n0 + i) * 264 + cb] = w4;
        }
    }
    __syncthreads();

    // ---- P10: proj MFMA (A=ws_pj hi/lo, B=o hi) + bias + residual ----
    {
        f32x4 pacc[2][2];
        #pragma unroll
        for (int i = 0; i < 2; ++i)
            #pragma unroll
            for (int nt = 0; nt < 2; ++nt)
                #pragma unroll
                for (int r = 0; r < 4; ++r) pacc[i][nt][r] = 0.f;
        for (int kt = 0; kt < 8; ++kt) {
            int bo = kt * 32 + kg * 8;
            bf16x8 o0 = *reinterpret_cast<const bf16x8*>(&smu[U_O + col * 264 + bo]);
            bf16x8 o1 = *reinterpret_cast<const bf16x8*>(&smu[U_O + (col + 16) * 264 + bo]);
            #pragma unroll
            for (int i = 0; i < 2; ++i) {
                const u16* ap = wspj + (((wv * 2 + i) * 8 + kt) * 64 + ln) * 16;
                bf16x8 ah = *reinterpret_cast<const bf16x8*>(ap);
                bf16x8 al = *reinterpret_cast<const bf16x8*>(ap + 8);
                pacc[i][0] = MFMA(ah, o0, pacc[i][0]);
                pacc[i][0] = MFMA(al, o0, pacc[i][0]);
                pacc[i][1] = MFMA(ah, o1, pacc[i][1]);
                pacc[i][1] = MFMA(al, o1, pacc[i][1]);
            }
        }
        #pragma unroll
        for (int i = 0; i < 2; ++i) {
            #pragma unroll
            for (int nt = 0; nt < 2; ++nt) {
                int v = nt * 16 + col;
                if (v < V_) {
                    #pragma unroll
                    for (int r = 0; r < 4; ++r) {
                        int row = (wv * 2 + i) * 16 + kg * 4 + r;
                        int idx = xbase + row * TV_ + v;
                        out[idx] = pacc[i][nt][r] + pjb[row] + x[idx];
                    }
                }
            }
        }
    }
}

extern "C" void kernel_launch(void* const* d_in, const int* in_sizes, int n_in,
                              void* d_out, int out_size, void* d_ws, size_t ws_size,
                              hipStream_t stream) {
    const float* x     = (const float*)d_in[0];
    const float* jl    = (const float*)d_in[1];
    const int*   hops  = (const int*)  d_in[2];
    const float* n1w   = (const float*)d_in[3];
    const float* n1b   = (const float*)d_in[4];
    const float* qw    = (const float*)d_in[5];
    const float* kvw   = (const float*)d_in[6];
    const float* pjw   = (const float*)d_in[7];
    const float* pjb   = (const float*)d_in[8];
    const float* rpe   = (const float*)d_in[9];
    const float* w1    = (const float*)d_in[10];
    const float* outer = (const float*)d_in[11];
    const float* alpha = (const float*)d_in[12];
    const float* pew   = (const float*)d_in[13];
    u16* ws = (u16*)d_ws;

    wprep<<<160, 256, 0, stream>>>(qw, kvw, pew, pjw, ws);
    fused_sttr<<<N_ * T_, 512, 0, stream>>>(x, jl, hops, n1w, n1b, rpe, pjb,
                                            w1, outer, alpha, ws, (float*)d_out);
}